// Round 14
// baseline (492.494 us; speedup 1.0000x reference)
//
#include <hip/hip_runtime.h>
#include <hip/hip_fp16.h>
#include <math.h>

#define NF 128
#define NC 40
#define NBLK 512   // p1 blocks, each owns a private slab
#define SCAP 1024  // per-(block,partition) slab capacity (mean 390, +33 sigma)
#define HSZ 12512  // LDS histogram capacity >= ceil(n/8)

typedef unsigned short bfraw;
typedef float f32x4 __attribute__((ext_vector_type(4)));
typedef short s16x8 __attribute__((ext_vector_type(8)));

__device__ __forceinline__ float bfLo(unsigned u) {
  return __uint_as_float(u << 16);
}
__device__ __forceinline__ float bfHi(unsigned u) {
  return __uint_as_float(u & 0xffff0000u);
}
__device__ __forceinline__ unsigned short f2bf(float f) {
  unsigned u = __float_as_uint(f);
  u += 0x7fff + ((u >> 16) & 1);  // RNE
  return (unsigned short)(u >> 16);
}
// weight in [0,1): positive fp16, 15 bits (no sign)
__device__ __forceinline__ unsigned short f2h15(float f) {
  __half h = __float2half(f);
  __half_raw hr = static_cast<__half_raw>(h);
  return (unsigned short)(hr.x & 0x7FFF);
}
__device__ __forceinline__ float h15tof(unsigned rec) {
  __half_raw hr;
  hr.x = (unsigned short)(rec & 0x7FFF);
  __half h = static_cast<__half>(hr);
  return __half2float(h);
}

// ---------------- CSR build: P1 — pure stream + slab append (NO global atomics) ----------------

__global__ __launch_bounds__(256) void p1_kernel(const int* __restrict__ src,
                                                 const int* __restrict__ tgt,
                                                 const float* __restrict__ mw,
                                                 int* __restrict__ slabcnt,
                                                 long long* __restrict__ slab,
                                                 int e, int n) {
  __shared__ int lcnt[8];
  int B = blockIdx.x;
  int tid = threadIdx.x;
  int lane = tid & 63;
  if (tid < 8) lcnt[tid] = 0;
  __syncthreads();
  int lo = (int)(((long long)e * B) / NBLK);
  int hi = (int)(((long long)e * (B + 1)) / NBLK);
  unsigned long long below = (lane == 0) ? 0ULL : ((~0ULL) >> (64 - lane));
  long long* myslab = slab + (size_t)B * 8 * SCAP;
  for (int i0 = lo; i0 < hi; i0 += 256) {
    int i = i0 + tid;
    bool active = i < hi;
    int t = 0, sr = 0;
    float w = 0.f;
    if (active) {
      t = __builtin_nontemporal_load(&tgt[i]);
      sr = __builtin_nontemporal_load(&src[i]);
      w = __builtin_nontemporal_load(&mw[i]);
    }
    int pp = active ? (int)(((long long)t * 8) / n) : -1;
    long long v = ((long long)t << 32) |
                  (long long)(((unsigned)sr << 15) | f2h15(w));
    #pragma unroll
    for (int q = 0; q < 8; ++q) {
      unsigned long long m = __ballot(pp == q);
      if (pp == q) {
        int leader = __ffsll((unsigned long long)m) - 1;
        int base = 0;
        if (lane == leader) base = atomicAdd(&lcnt[q], (int)__popcll(m));  // LDS atomic
        base = __shfl(base, leader);
        int pos = base + (int)__popcll(m & below);
        if (pos < SCAP) myslab[(size_t)q * SCAP + pos] = v;
      }
    }
  }
  __syncthreads();
  if (tid < 8) {
    int c = lcnt[tid];
    slabcnt[B * 8 + tid] = (c < SCAP) ? c : SCAP;
  }
}

// ---------------- CSR build: count2 — slab -> LDS histogram -> dense XCD-local flush ----------------
// grid = 64 blocks; partition p = blockIdx&7 pinned to one XCD; 8 sub-blocks per partition.

__global__ __launch_bounds__(256) void count2_kernel(const long long* __restrict__ slab,
                                                     const int* __restrict__ slabcnt,
                                                     int* __restrict__ cnt, int n) {
  __shared__ int hist[HSZ];
  int p = blockIdx.x & 7;
  int sub = blockIdx.x >> 3;
  int tid = threadIdx.x;
  int lo = (int)(((long long)n * p) >> 3);
  int hi = (int)(((long long)n * (p + 1)) >> 3);
  int sz = hi - lo;
  for (int j = tid; j < sz; j += 256) hist[j] = 0;
  __syncthreads();
  for (int B = sub; B < NBLK; B += 8) {
    int cb = slabcnt[B * 8 + p];
    const long long* sb = slab + ((size_t)B * 8 + p) * SCAP;
    for (int i = tid; i < cb; i += 256) {
      long long v = __builtin_nontemporal_load(&sb[i]);
      atomicAdd(&hist[(int)(v >> 32) - lo], 1);  // LDS atomic
    }
  }
  __syncthreads();
  for (int j = tid; j < sz; j += 256) {
    int h = hist[j];
    if (h) atomicAdd(&cnt[lo + j], h);  // dense, same-XCD lines
  }
}

// ---------------- CSR build: P2 — dense slab stream -> L2-local scatter ----------------

__global__ __launch_bounds__(256) void p2_kernel(const long long* __restrict__ slab,
                                                 const int* __restrict__ slabcnt,
                                                 int* __restrict__ cursor,
                                                 unsigned* __restrict__ ecsr) {
  int p = blockIdx.x & 7;       // partition -> XCD (round-robin dispatch)
  int nsub = gridDim.x >> 3;
  int bsub = blockIdx.x >> 3;
  for (int B = bsub; B < NBLK; B += nsub) {
    int cb = slabcnt[B * 8 + p];
    const long long* sb = slab + ((size_t)B * 8 + p) * SCAP;
    for (int i = threadIdx.x; i < cb; i += 256) {
      long long v = __builtin_nontemporal_load(&sb[i]);
      int t = (int)(v >> 32);
      int pos = atomicAdd(&cursor[t], 1);
      ecsr[pos] = (unsigned)(v & 0xffffffffLL);
    }
  }
}

// ---------------- scans ----------------

__global__ __launch_bounds__(1024) void scan1_kernel(const int* __restrict__ cnt,
                                                     int* __restrict__ rp,
                                                     int* __restrict__ bsum, int n) {
  __shared__ int wsum[16];
  int tid = threadIdx.x, lane = tid & 63, wid = tid >> 6;
  int i = blockIdx.x * 1024 + tid;
  int v = (i < n) ? cnt[i] : 0;
  int x = v;
  #pragma unroll
  for (int off = 1; off < 64; off <<= 1) {
    int t = __shfl_up(x, off);
    if (lane >= off) x += t;
  }
  if (lane == 63) wsum[wid] = x;
  __syncthreads();
  if (wid == 0) {
    int ws = (lane < 16) ? wsum[lane] : 0;
    int y = ws;
    #pragma unroll
    for (int off = 1; off < 16; off <<= 1) {
      int t = __shfl_up(y, off);
      if (lane >= off) y += t;
    }
    if (lane < 16) wsum[lane] = y - ws;
  }
  __syncthreads();
  int incl = x + wsum[wid];
  if (i < n) rp[i] = incl - v;
  if (tid == 1023) bsum[blockIdx.x] = incl;
}

__global__ __launch_bounds__(1024) void scan2_kernel(int* __restrict__ bsum, int nb,
                                                     int* __restrict__ rp_n) {
  __shared__ int wsum[16];
  int tid = threadIdx.x, lane = tid & 63, wid = tid >> 6;
  int v = (tid < nb) ? bsum[tid] : 0;
  int x = v;
  #pragma unroll
  for (int off = 1; off < 64; off <<= 1) {
    int t = __shfl_up(x, off);
    if (lane >= off) x += t;
  }
  if (lane == 63) wsum[wid] = x;
  __syncthreads();
  if (wid == 0) {
    int ws = (lane < 16) ? wsum[lane] : 0;
    int y = ws;
    #pragma unroll
    for (int off = 1; off < 16; off <<= 1) {
      int t = __shfl_up(y, off);
      if (lane >= off) y += t;
    }
    if (lane < 16) wsum[lane] = y - ws;
  }
  __syncthreads();
  int incl = x + wsum[wid];
  if (tid < nb) bsum[tid] = incl - v;
  if (tid == 1023) *rp_n = incl;
}

__global__ __launch_bounds__(256) void scan3_kernel(int* __restrict__ rp,
                                                    int* __restrict__ cursor,
                                                    const int* __restrict__ bsum, int n) {
  int i = blockIdx.x * 256 + threadIdx.x;
  if (i < n) {
    int v = rp[i] + bsum[i >> 10];
    rp[i] = v;
    cursor[i] = v;
  }
}

// ---------------- weight pack: W[128][128] fp32 -> B-fragment bf16 layout ----------------

__global__ __launch_bounds__(256) void wpack_kernel(const float* __restrict__ W0,
                                                    const float* __restrict__ W1,
                                                    const float* __restrict__ W2,
                                                    bfraw* __restrict__ Wb) {
  int id = blockIdx.x * 256 + threadIdx.x;
  if (id >= 3 * NF * NF) return;
  int w = id >> 14;
  int el = id & 16383;
  int k = el >> 7;
  int col = el & 127;
  const float* W = (w == 0) ? W0 : ((w == 1) ? W1 : W2);
  float v = W[k * NF + col];
  int ct = col >> 4;
  int kt = k >> 5;
  int g = (k & 31) >> 3;
  int j = k & 7;
  int ln = g * 16 + (col & 15);
  Wb[((((w * 8 + ct) * 4 + kt) * 64) + ln) * 8 + j] = f2bf(v);
}

// W3[128][40] fp32 -> B-frag layout over 48 cols (cols 40..47 zero)
__global__ __launch_bounds__(256) void wpack40_kernel(const float* __restrict__ W3,
                                                      bfraw* __restrict__ Wb3) {
  int id = blockIdx.x * 256 + threadIdx.x;
  if (id >= NF * 48) return;
  int k = id / 48;
  int col = id % 48;
  float v = (col < NC) ? W3[k * NC + col] : 0.f;
  int ct = col >> 4;
  int kt = k >> 5;
  int g = (k & 31) >> 3;
  int j = k & 7;
  int ln = g * 16 + (col & 15);
  Wb3[(((ct * 4 + kt) * 64) + ln) * 8 + j] = f2bf(v);
}

// ---------------- MFMA GEMM: Tb[n][128](bf16) = X[n][128] @ W[128][128] ----------------

template <bool INF32>
__global__ __launch_bounds__(256) void gemm128_mfma_kernel(const void* __restrict__ Xv,
                                                           const bfraw* __restrict__ Wb,
                                                           bfraw* __restrict__ Tb, int n) {
  __shared__ __align__(16) bfraw stage[4][16][NF + 8];
  int wv = threadIdx.x >> 6;
  int lane = threadIdx.x & 63;
  int rowBase = blockIdx.x * 64 + wv * 16;
  int arow = rowBase + (lane & 15);
  int g = lane >> 4;
  bool rv = arow < n;

  s16x8 afrag[4];
  #pragma unroll
  for (int kt = 0; kt < 4; ++kt) {
    s16x8 t = {0, 0, 0, 0, 0, 0, 0, 0};
    if (rv) {
      if (INF32) {
        const float* xr = (const float*)Xv + (size_t)arow * NF + kt * 32 + g * 8;
        float4 x0 = *(const float4*)xr;
        float4 x1 = *(const float4*)(xr + 4);
        t[0] = (short)f2bf(x0.x); t[1] = (short)f2bf(x0.y);
        t[2] = (short)f2bf(x0.z); t[3] = (short)f2bf(x0.w);
        t[4] = (short)f2bf(x1.x); t[5] = (short)f2bf(x1.y);
        t[6] = (short)f2bf(x1.z); t[7] = (short)f2bf(x1.w);
      } else {
        t = *(const s16x8*)((const bfraw*)Xv + (size_t)arow * NF + kt * 32 + g * 8);
      }
    }
    afrag[kt] = t;
  }

  #pragma unroll
  for (int ct = 0; ct < 8; ++ct) {
    f32x4 acc = {0.f, 0.f, 0.f, 0.f};
    #pragma unroll
    for (int kt = 0; kt < 4; ++kt) {
      s16x8 b = *(const s16x8*)&Wb[(((ct * 4 + kt) * 64) + lane) * 8];
      acc = __builtin_amdgcn_mfma_f32_16x16x32_bf16(afrag[kt], b, acc, 0, 0, 0);
    }
    #pragma unroll
    for (int r = 0; r < 4; ++r) {
      stage[wv][g * 4 + r][ct * 16 + (lane & 15)] = f2bf(acc[r]);
    }
  }
  __syncthreads();
  int rr = lane >> 2;
  int cc = (lane & 3) * 32;
  int grow = rowBase + rr;
  if (grow < n) {
    #pragma unroll
    for (int q = 0; q < 4; ++q) {
      uint4 v = *(const uint4*)&stage[wv][rr][cc + q * 8];
      *(uint4*)&Tb[(size_t)grow * NF + cc + q * 8] = v;
    }
  }
}

// ---------------- MFMA GEMM: T40[n][64](bf16) = h2[n][128] @ W3pad[128][48] ----------------

__global__ __launch_bounds__(256) void gemm40_mfma_kernel(const bfraw* __restrict__ X,
                                                          const bfraw* __restrict__ Wb3,
                                                          bfraw* __restrict__ T40, int n) {
  __shared__ __align__(16) bfraw stage[4][16][72];
  int wv = threadIdx.x >> 6;
  int lane = threadIdx.x & 63;
  int rowBase = blockIdx.x * 64 + wv * 16;
  int arow = rowBase + (lane & 15);
  int g = lane >> 4;
  bool rv = arow < n;

  s16x8 afrag[4];
  #pragma unroll
  for (int kt = 0; kt < 4; ++kt) {
    s16x8 t = {0, 0, 0, 0, 0, 0, 0, 0};
    if (rv) t = *(const s16x8*)&X[(size_t)arow * NF + kt * 32 + g * 8];
    afrag[kt] = t;
  }

  #pragma unroll
  for (int ct = 0; ct < 3; ++ct) {
    f32x4 acc = {0.f, 0.f, 0.f, 0.f};
    #pragma unroll
    for (int kt = 0; kt < 4; ++kt) {
      s16x8 b = *(const s16x8*)&Wb3[(((ct * 4 + kt) * 64) + lane) * 8];
      acc = __builtin_amdgcn_mfma_f32_16x16x32_bf16(afrag[kt], b, acc, 0, 0, 0);
    }
    #pragma unroll
    for (int r = 0; r < 4; ++r) {
      stage[wv][g * 4 + r][ct * 16 + (lane & 15)] = f2bf(acc[r]);
    }
  }
  #pragma unroll
  for (int r = 0; r < 4; ++r) stage[wv][g * 4 + r][48 + (lane & 15)] = 0;
  __syncthreads();
  int rr = lane >> 2;
  int cc = (lane & 3) * 16;
  int grow = rowBase + rr;
  if (grow < n) {
    uint4 v0 = *(const uint4*)&stage[wv][rr][cc];
    uint4 v1 = *(const uint4*)&stage[wv][rr][cc + 8];
    *(uint4*)&T40[(size_t)grow * 64 + cc] = v0;
    *(uint4*)&T40[(size_t)grow * 64 + cc + 8] = v1;
  }
}

// ---------------- aggregation (pull), bf16 gather, node-major, 128 feats ----------------

template <bool RELU, bool RES, bool BIAS, bool OUTBF>
__global__ __launch_bounds__(256) void agg128_kernel(const bfraw* __restrict__ Tb,
                                                     const int* __restrict__ rp,
                                                     const unsigned* __restrict__ ecsr,
                                                     const float* __restrict__ bias,
                                                     const bfraw* __restrict__ Hres,
                                                     void* __restrict__ HoutV, int n) {
  int node = (blockIdx.x * 256 + threadIdx.x) >> 6;
  int lane = threadIdx.x & 63;
  if (node >= n) return;
  int st = lane >> 4;  // edge-stream 0..3
  int fl = lane & 15;  // features 8*fl .. 8*fl+7
  int beg = rp[node], end = rp[node + 1];
  float a[8];
  #pragma unroll
  for (int i = 0; i < 8; ++i) a[i] = 0.f;
  int eidx = beg + st;
  for (; eidx + 4 < end; eidx += 8) {
    unsigned e0 = __builtin_nontemporal_load(&ecsr[eidx]);
    unsigned e1 = __builtin_nontemporal_load(&ecsr[eidx + 4]);
    float w0 = h15tof(e0);
    float w1 = h15tof(e1);
    uint4 q0 = *(const uint4*)&Tb[(size_t)(e0 >> 15) * NF + fl * 8];
    uint4 q1 = *(const uint4*)&Tb[(size_t)(e1 >> 15) * NF + fl * 8];
    a[0] = fmaf(w0, bfLo(q0.x), a[0]); a[1] = fmaf(w0, bfHi(q0.x), a[1]);
    a[2] = fmaf(w0, bfLo(q0.y), a[2]); a[3] = fmaf(w0, bfHi(q0.y), a[3]);
    a[4] = fmaf(w0, bfLo(q0.z), a[4]); a[5] = fmaf(w0, bfHi(q0.z), a[5]);
    a[6] = fmaf(w0, bfLo(q0.w), a[6]); a[7] = fmaf(w0, bfHi(q0.w), a[7]);
    a[0] = fmaf(w1, bfLo(q1.x), a[0]); a[1] = fmaf(w1, bfHi(q1.x), a[1]);
    a[2] = fmaf(w1, bfLo(q1.y), a[2]); a[3] = fmaf(w1, bfHi(q1.y), a[3]);
    a[4] = fmaf(w1, bfLo(q1.z), a[4]); a[5] = fmaf(w1, bfHi(q1.z), a[5]);
    a[6] = fmaf(w1, bfLo(q1.w), a[6]); a[7] = fmaf(w1, bfHi(q1.w), a[7]);
  }
  if (eidx < end) {
    unsigned e0 = __builtin_nontemporal_load(&ecsr[eidx]);
    float w0 = h15tof(e0);
    uint4 q0 = *(const uint4*)&Tb[(size_t)(e0 >> 15) * NF + fl * 8];
    a[0] = fmaf(w0, bfLo(q0.x), a[0]); a[1] = fmaf(w0, bfHi(q0.x), a[1]);
    a[2] = fmaf(w0, bfLo(q0.y), a[2]); a[3] = fmaf(w0, bfHi(q0.y), a[3]);
    a[4] = fmaf(w0, bfLo(q0.z), a[4]); a[5] = fmaf(w0, bfHi(q0.z), a[5]);
    a[6] = fmaf(w0, bfLo(q0.w), a[6]); a[7] = fmaf(w0, bfHi(q0.w), a[7]);
  }
  #pragma unroll
  for (int i = 0; i < 8; ++i) {
    a[i] += __shfl_xor(a[i], 16);
    a[i] += __shfl_xor(a[i], 32);
  }
  if (st == 0) {
    if (BIAS) {
      float4 b0 = *(const float4*)&bias[fl * 8];
      float4 b1 = *(const float4*)&bias[fl * 8 + 4];
      a[0] += b0.x; a[1] += b0.y; a[2] += b0.z; a[3] += b0.w;
      a[4] += b1.x; a[5] += b1.y; a[6] += b1.z; a[7] += b1.w;
    }
    if (RELU) {
      #pragma unroll
      for (int i = 0; i < 8; ++i) a[i] = fmaxf(a[i], 0.f);
    }
    if (RES) {
      uint4 r = *(const uint4*)&Hres[(size_t)node * NF + fl * 8];
      a[0] += bfLo(r.x); a[1] += bfHi(r.x);
      a[2] += bfLo(r.y); a[3] += bfHi(r.y);
      a[4] += bfLo(r.z); a[5] += bfHi(r.z);
      a[6] += bfLo(r.w); a[7] += bfHi(r.w);
    }
    if (OUTBF) {
      bfraw* Hout = (bfraw*)HoutV;
      uint4 o;
      o.x = ((unsigned)f2bf(a[1]) << 16) | f2bf(a[0]);
      o.y = ((unsigned)f2bf(a[3]) << 16) | f2bf(a[2]);
      o.z = ((unsigned)f2bf(a[5]) << 16) | f2bf(a[4]);
      o.w = ((unsigned)f2bf(a[7]) << 16) | f2bf(a[6]);
      *(uint4*)&Hout[(size_t)node * NF + fl * 8] = o;
    } else {
      float* Hout = (float*)HoutV;
      float4 o0, o1;
      o0.x = a[0]; o0.y = a[1]; o0.z = a[2]; o0.w = a[3];
      o1.x = a[4]; o1.y = a[5]; o1.z = a[6]; o1.w = a[7];
      *(float4*)&Hout[(size_t)node * NF + fl * 8] = o0;
      *(float4*)&Hout[(size_t)node * NF + fl * 8 + 4] = o1;
    }
  }
}

// ---------------- final: out = log_softmax(agg40(T40) + b3) ----------------

__global__ __launch_bounds__(256) void agg40_lsm_kernel(const bfraw* __restrict__ T40,
                                                        const int* __restrict__ rp,
                                                        const unsigned* __restrict__ ecsr,
                                                        const float* __restrict__ bias,
                                                        float* __restrict__ out, int n) {
  int node = (blockIdx.x * 256 + threadIdx.x) >> 6;
  int lane = threadIdx.x & 63;
  if (node >= n) return;
  int st = lane >> 4;  // edge-stream 0..3
  int fl = lane & 15;  // cols 4*fl .. 4*fl+3
  int beg = rp[node], end = rp[node + 1];
  float a0 = 0.f, a1 = 0.f, a2 = 0.f, a3 = 0.f;
  int eidx = beg + st;
  for (; eidx + 4 < end; eidx += 8) {
    unsigned e0 = __builtin_nontemporal_load(&ecsr[eidx]);
    unsigned e1 = __builtin_nontemporal_load(&ecsr[eidx + 4]);
    float w0 = h15tof(e0);
    float w1 = h15tof(e1);
    uint2 q0 = *(const uint2*)&T40[(size_t)(e0 >> 15) * 64 + fl * 4];
    uint2 q1 = *(const uint2*)&T40[(size_t)(e1 >> 15) * 64 + fl * 4];
    a0 = fmaf(w0, bfLo(q0.x), a0); a1 = fmaf(w0, bfHi(q0.x), a1);
    a2 = fmaf(w0, bfLo(q0.y), a2); a3 = fmaf(w0, bfHi(q0.y), a3);
    a0 = fmaf(w1, bfLo(q1.x), a0); a1 = fmaf(w1, bfHi(q1.x), a1);
    a2 = fmaf(w1, bfLo(q1.y), a2); a3 = fmaf(w1, bfHi(q1.y), a3);
  }
  if (eidx < end) {
    unsigned e0 = __builtin_nontemporal_load(&ecsr[eidx]);
    float w0 = h15tof(e0);
    uint2 q0 = *(const uint2*)&T40[(size_t)(e0 >> 15) * 64 + fl * 4];
    a0 = fmaf(w0, bfLo(q0.x), a0); a1 = fmaf(w0, bfHi(q0.x), a1);
    a2 = fmaf(w0, bfLo(q0.y), a2); a3 = fmaf(w0, bfHi(q0.y), a3);
  }
  a0 += __shfl_xor(a0, 16); a0 += __shfl_xor(a0, 32);
  a1 += __shfl_xor(a1, 16); a1 += __shfl_xor(a1, 32);
  a2 += __shfl_xor(a2, 16); a2 += __shfl_xor(a2, 32);
  a3 += __shfl_xor(a3, 16); a3 += __shfl_xor(a3, 32);
  if (st == 0) {
    bool v = fl < 10;
    if (v) {
      float4 b = *(const float4*)&bias[fl * 4];
      a0 += b.x; a1 += b.y; a2 += b.z; a3 += b.w;
    }
    float lm = v ? fmaxf(fmaxf(a0, a1), fmaxf(a2, a3)) : -INFINITY;
    #pragma unroll
    for (int off = 1; off < 16; off <<= 1) lm = fmaxf(lm, __shfl_xor(lm, off));
    float ls = v ? (expf(a0 - lm) + expf(a1 - lm) + expf(a2 - lm) + expf(a3 - lm)) : 0.f;
    #pragma unroll
    for (int off = 1; off < 16; off <<= 1) ls += __shfl_xor(ls, off);
    float lse = lm + logf(ls);
    if (v) {
      float4 o;
      o.x = a0 - lse; o.y = a1 - lse; o.z = a2 - lse; o.w = a3 - lse;
      *(float4*)&out[(size_t)node * NC + fl * 4] = o;
    }
  }
}

// ---------------- launch ----------------

extern "C" void kernel_launch(void* const* d_in, const int* in_sizes, int n_in,
                              void* d_out, int out_size, void* d_ws, size_t ws_size,
                              hipStream_t stream) {
  const float* x   = (const float*)d_in[0];
  const int*   src = (const int*)d_in[1];
  const int*   tgt = (const int*)d_in[2];
  const float* mw  = (const float*)d_in[3];
  const float* W0  = (const float*)d_in[4];
  const float* b0  = (const float*)d_in[5];
  const float* W1  = (const float*)d_in[6];
  const float* b1  = (const float*)d_in[7];
  const float* W2  = (const float*)d_in[8];
  const float* b2  = (const float*)d_in[9];
  const float* W3  = (const float*)d_in[10];
  const float* b3  = (const float*)d_in[11];
  int n = in_sizes[0] / NF;
  int e = in_sizes[1];
  float* out = (float*)d_out;

  char* ws = (char*)d_ws;
  size_t nbB = (((size_t)n * NF * sizeof(bfraw)) + 255) / 256 * 256; // bf16 [N,128]
  bfraw* bufT  = (bfraw*)(ws);                   // transform out (bf16), also T40 (stride 64)
  bfraw* bufH0 = (bfraw*)(ws + nbB);             // h0 / h2
  bfraw* bufH1 = (bfraw*)(ws + 2 * nbB);         // h1
  // slab staging aliases bufH0+bufH1 (dead until after P2): 512*8*1024*8 = 33.5 MB
  long long* slab = (long long*)(ws + nbB);
  char* p = ws + 3 * nbB;
  bfraw* Wb = (bfraw*)p;   // 3 gemm128 packs + 1 gemm40 pack
  p += (((3 * 8 + 3) * 4 * 64 * 8 * sizeof(bfraw)) + 255) / 256 * 256;
  int* rp = (int*)p;      p += (((size_t)(n + 1) * 4) + 255) / 256 * 256;
  int* fill = (int*)p;    p += (((size_t)n * 4) + 255) / 256 * 256;
  int* bsum = (int*)p;    p += 4096;
  int* slabcnt = (int*)p; p += ((NBLK * 8 * 4) + 255) / 256 * 256;
  unsigned* ecsr = (unsigned*)p;

  bfraw* Wb3 = Wb + 3 * 8 * 4 * 64 * 8;

  hipMemsetAsync(fill, 0, (size_t)n * 4, stream);
  int nb1 = (n + 1023) / 1024;
  wpack_kernel<<<(3 * NF * NF + 255) / 256, 256, 0, stream>>>(W0, W1, W2, Wb);
  wpack40_kernel<<<(NF * 48 + 255) / 256, 256, 0, stream>>>(W3, Wb3);
  p1_kernel<<<NBLK, 256, 0, stream>>>(src, tgt, mw, slabcnt, slab, e, n);
  count2_kernel<<<64, 256, 0, stream>>>(slab, slabcnt, fill, n);
  scan1_kernel<<<nb1, 1024, 0, stream>>>(fill, rp, bsum, n);
  scan2_kernel<<<1, 1024, 0, stream>>>(bsum, nb1, &rp[n]);
  scan3_kernel<<<(n + 255) / 256, 256, 0, stream>>>(rp, fill, bsum, n);
  p2_kernel<<<NBLK, 256, 0, stream>>>(slab, slabcnt, fill, ecsr);

  int gb = (n + 63) / 64;
  int ab = (n + 3) / 4;
  // L0: h0 = relu(agg(x@W0) + b0)                       (h0 bf16)
  gemm128_mfma_kernel<true><<<gb, 256, 0, stream>>>(x, Wb, bufT, n);
  agg128_kernel<true, false, true, true><<<ab, 256, 0, stream>>>(
      bufT, rp, ecsr, b0, nullptr, bufH0, n);
  // L1: h1 = relu(agg(h0@W1) + b1) + h0                 (h1 bf16)
  gemm128_mfma_kernel<false><<<gb, 256, 0, stream>>>(bufH0, Wb + 8 * 4 * 64 * 8, bufT, n);
  agg128_kernel<true, true, true, true><<<ab, 256, 0, stream>>>(
      bufT, rp, ecsr, b1, bufH0, bufH1, n);
  // L2: h2 = relu(agg(h1@W2) + b2) + h1                 (h2 bf16, reuses h0 buf)
  gemm128_mfma_kernel<false><<<gb, 256, 0, stream>>>(bufH1, Wb + 2 * 8 * 4 * 64 * 8, bufT, n);
  agg128_kernel<true, true, true, true><<<ab, 256, 0, stream>>>(
      bufT, rp, ecsr, b2, bufH1, bufH0, n);
  // Final: T40 = h2 @ W3pad (bf16, stride 64) ; out = log_softmax(agg40(T40) + b3)
  gemm40_mfma_kernel<<<gb, 256, 0, stream>>>(bufH0, Wb3, bufT, n);
  agg40_lsm_kernel<<<ab, 256, 0, stream>>>(bufT, rp, ecsr, b3, out, n);
}

// Round 16
// 462.525 us; speedup vs baseline: 1.0648x; 1.0648x over previous
//
#include <hip/hip_runtime.h>
#include <hip/hip_fp16.h>
#include <math.h>

#define NF 128
#define NC 40
#define NBLK 512   // p1 blocks, each owns a private slab
#define SCAP 1024  // per-(block,partition) slab capacity (mean 390, +33 sigma)
#define HSZ 12512  // LDS histogram capacity >= ceil(n/8)

typedef unsigned short bfraw;
typedef float f32x4 __attribute__((ext_vector_type(4)));
typedef short s16x8 __attribute__((ext_vector_type(8)));

__device__ __forceinline__ float bfLo(unsigned u) {
  return __uint_as_float(u << 16);
}
__device__ __forceinline__ float bfHi(unsigned u) {
  return __uint_as_float(u & 0xffff0000u);
}
__device__ __forceinline__ unsigned short f2bf(float f) {
  unsigned u = __float_as_uint(f);
  u += 0x7fff + ((u >> 16) & 1);  // RNE
  return (unsigned short)(u >> 16);
}
// weight in [0,1): positive fp16, 15 bits (no sign)
__device__ __forceinline__ unsigned short f2h15(float f) {
  __half h = __float2half(f);
  __half_raw hr = static_cast<__half_raw>(h);
  return (unsigned short)(hr.x & 0x7FFF);
}
__device__ __forceinline__ float h15tof(unsigned rec) {
  __half_raw hr;
  hr.x = (unsigned short)(rec & 0x7FFF);
  __half h = static_cast<__half>(hr);
  return __half2float(h);
}

// ---------------- CSR build: P1 — pure stream + slab append (NO global atomics) ----------------

__global__ __launch_bounds__(256) void p1_kernel(const int* __restrict__ src,
                                                 const int* __restrict__ tgt,
                                                 const float* __restrict__ mw,
                                                 int* __restrict__ slabcnt,
                                                 long long* __restrict__ slab,
                                                 int e, int n) {
  __shared__ int lcnt[8];
  int B = blockIdx.x;
  int tid = threadIdx.x;
  int lane = tid & 63;
  if (tid < 8) lcnt[tid] = 0;
  __syncthreads();
  int lo = (int)(((long long)e * B) / NBLK);
  int hi = (int)(((long long)e * (B + 1)) / NBLK);
  unsigned long long below = (lane == 0) ? 0ULL : ((~0ULL) >> (64 - lane));
  long long* myslab = slab + (size_t)B * 8 * SCAP;
  for (int i0 = lo; i0 < hi; i0 += 256) {
    int i = i0 + tid;
    bool active = i < hi;
    int t = 0, sr = 0;
    float w = 0.f;
    if (active) {
      t = __builtin_nontemporal_load(&tgt[i]);
      sr = __builtin_nontemporal_load(&src[i]);
      w = __builtin_nontemporal_load(&mw[i]);
    }
    int pp = active ? (int)(((long long)t * 8) / n) : -1;
    long long v = ((long long)t << 32) |
                  (long long)(((unsigned)sr << 15) | f2h15(w));
    #pragma unroll
    for (int q = 0; q < 8; ++q) {
      unsigned long long m = __ballot(pp == q);
      if (pp == q) {
        int leader = __ffsll((unsigned long long)m) - 1;
        int base = 0;
        if (lane == leader) base = atomicAdd(&lcnt[q], (int)__popcll(m));  // LDS atomic
        base = __shfl(base, leader);
        int pos = base + (int)__popcll(m & below);
        if (pos < SCAP) myslab[(size_t)q * SCAP + pos] = v;
      }
    }
  }
  __syncthreads();
  if (tid < 8) {
    int c = lcnt[tid];
    slabcnt[B * 8 + tid] = (c < SCAP) ? c : SCAP;
  }
}

// ---------------- CSR build: count2 — slab -> LDS histogram -> dense XCD-local flush ----------------

__global__ __launch_bounds__(256) void count2_kernel(const long long* __restrict__ slab,
                                                     const int* __restrict__ slabcnt,
                                                     int* __restrict__ cnt, int n) {
  __shared__ int hist[HSZ];
  int p = blockIdx.x & 7;
  int sub = blockIdx.x >> 3;
  int nsub = gridDim.x >> 3;
  int tid = threadIdx.x;
  int lo = (int)(((long long)n * p) >> 3);
  int hi = (int)(((long long)n * (p + 1)) >> 3);
  int sz = hi - lo;
  for (int j = tid; j < sz; j += 256) hist[j] = 0;
  __syncthreads();
  for (int B = sub; B < NBLK; B += nsub) {
    int cb = slabcnt[B * 8 + p];
    const long long* sb = slab + ((size_t)B * 8 + p) * SCAP;
    for (int i = tid; i < cb; i += 256) {
      long long v = __builtin_nontemporal_load(&sb[i]);
      atomicAdd(&hist[(int)(v >> 32) - lo], 1);  // LDS atomic
    }
  }
  __syncthreads();
  for (int j = tid; j < sz; j += 256) {
    int h = hist[j];
    if (h) atomicAdd(&cnt[lo + j], h);  // dense, same-XCD lines
  }
}

// ---------------- CSR build: P2 — dense slab stream -> L2-local scatter ----------------

__global__ __launch_bounds__(256) void p2_kernel(const long long* __restrict__ slab,
                                                 const int* __restrict__ slabcnt,
                                                 int* __restrict__ cursor,
                                                 unsigned* __restrict__ ecsr) {
  int p = blockIdx.x & 7;       // partition -> XCD (round-robin dispatch)
  int nsub = gridDim.x >> 3;
  int bsub = blockIdx.x >> 3;
  for (int B = bsub; B < NBLK; B += nsub) {
    int cb = slabcnt[B * 8 + p];
    const long long* sb = slab + ((size_t)B * 8 + p) * SCAP;
    for (int i = threadIdx.x; i < cb; i += 256) {
      long long v = __builtin_nontemporal_load(&sb[i]);
      int t = (int)(v >> 32);
      int pos = atomicAdd(&cursor[t], 1);
      ecsr[pos] = (unsigned)(v & 0xffffffffLL);
    }
  }
}

// ---------------- scans ----------------

__global__ __launch_bounds__(1024) void scan1_kernel(const int* __restrict__ cnt,
                                                     int* __restrict__ rp,
                                                     int* __restrict__ bsum, int n) {
  __shared__ int wsum[16];
  int tid = threadIdx.x, lane = tid & 63, wid = tid >> 6;
  int i = blockIdx.x * 1024 + tid;
  int v = (i < n) ? cnt[i] : 0;
  int x = v;
  #pragma unroll
  for (int off = 1; off < 64; off <<= 1) {
    int t = __shfl_up(x, off);
    if (lane >= off) x += t;
  }
  if (lane == 63) wsum[wid] = x;
  __syncthreads();
  if (wid == 0) {
    int ws = (lane < 16) ? wsum[lane] : 0;
    int y = ws;
    #pragma unroll
    for (int off = 1; off < 16; off <<= 1) {
      int t = __shfl_up(y, off);
      if (lane >= off) y += t;
    }
    if (lane < 16) wsum[lane] = y - ws;
  }
  __syncthreads();
  int incl = x + wsum[wid];
  if (i < n) rp[i] = incl - v;
  if (tid == 1023) bsum[blockIdx.x] = incl;
}

__global__ __launch_bounds__(1024) void scan2_kernel(int* __restrict__ bsum, int nb,
                                                     int* __restrict__ rp_n) {
  __shared__ int wsum[16];
  int tid = threadIdx.x, lane = tid & 63, wid = tid >> 6;
  int v = (tid < nb) ? bsum[tid] : 0;
  int x = v;
  #pragma unroll
  for (int off = 1; off < 64; off <<= 1) {
    int t = __shfl_up(x, off);
    if (lane >= off) x += t;
  }
  if (lane == 63) wsum[wid] = x;
  __syncthreads();
  if (wid == 0) {
    int ws = (lane < 16) ? wsum[lane] : 0;
    int y = ws;
    #pragma unroll
    for (int off = 1; off < 16; off <<= 1) {
      int t = __shfl_up(y, off);
      if (lane >= off) y += t;
    }
    if (lane < 16) wsum[lane] = y - ws;
  }
  __syncthreads();
  int incl = x + wsum[wid];
  if (tid < nb) bsum[tid] = incl - v;
  if (tid == 1023) *rp_n = incl;
}

__global__ __launch_bounds__(256) void scan3_kernel(int* __restrict__ rp,
                                                    int* __restrict__ cursor,
                                                    const int* __restrict__ bsum, int n) {
  int i = blockIdx.x * 256 + threadIdx.x;
  if (i < n) {
    int v = rp[i] + bsum[i >> 10];
    rp[i] = v;
    cursor[i] = v;
  }
}

// ---------------- weight pack: W[128][128] fp32 -> B-fragment bf16 layout ----------------

__global__ __launch_bounds__(256) void wpack_kernel(const float* __restrict__ W0,
                                                    const float* __restrict__ W1,
                                                    const float* __restrict__ W2,
                                                    bfraw* __restrict__ Wb) {
  int id = blockIdx.x * 256 + threadIdx.x;
  if (id >= 3 * NF * NF) return;
  int w = id >> 14;
  int el = id & 16383;
  int k = el >> 7;
  int col = el & 127;
  const float* W = (w == 0) ? W0 : ((w == 1) ? W1 : W2);
  float v = W[k * NF + col];
  int ct = col >> 4;
  int kt = k >> 5;
  int g = (k & 31) >> 3;
  int j = k & 7;
  int ln = g * 16 + (col & 15);
  Wb[((((w * 8 + ct) * 4 + kt) * 64) + ln) * 8 + j] = f2bf(v);
}

// W3[128][40] fp32 -> B-frag layout over 48 cols (cols 40..47 zero)
__global__ __launch_bounds__(256) void wpack40_kernel(const float* __restrict__ W3,
                                                      bfraw* __restrict__ Wb3) {
  int id = blockIdx.x * 256 + threadIdx.x;
  if (id >= NF * 48) return;
  int k = id / 48;
  int col = id % 48;
  float v = (col < NC) ? W3[k * NC + col] : 0.f;
  int ct = col >> 4;
  int kt = k >> 5;
  int g = (k & 31) >> 3;
  int j = k & 7;
  int ln = g * 16 + (col & 15);
  Wb3[(((ct * 4 + kt) * 64) + ln) * 8 + j] = f2bf(v);
}

// ---------------- MFMA GEMM: Tb[n][128](bf16) = X[n][128] @ W[128][128] ----------------

template <bool INF32>
__global__ __launch_bounds__(256) void gemm128_mfma_kernel(const void* __restrict__ Xv,
                                                           const bfraw* __restrict__ Wb,
                                                           bfraw* __restrict__ Tb, int n) {
  __shared__ __align__(16) bfraw stage[4][16][NF + 8];
  int wv = threadIdx.x >> 6;
  int lane = threadIdx.x & 63;
  int rowBase = blockIdx.x * 64 + wv * 16;
  int arow = rowBase + (lane & 15);
  int g = lane >> 4;
  bool rv = arow < n;

  s16x8 afrag[4];
  #pragma unroll
  for (int kt = 0; kt < 4; ++kt) {
    s16x8 t = {0, 0, 0, 0, 0, 0, 0, 0};
    if (rv) {
      if (INF32) {
        const float* xr = (const float*)Xv + (size_t)arow * NF + kt * 32 + g * 8;
        float4 x0 = *(const float4*)xr;
        float4 x1 = *(const float4*)(xr + 4);
        t[0] = (short)f2bf(x0.x); t[1] = (short)f2bf(x0.y);
        t[2] = (short)f2bf(x0.z); t[3] = (short)f2bf(x0.w);
        t[4] = (short)f2bf(x1.x); t[5] = (short)f2bf(x1.y);
        t[6] = (short)f2bf(x1.z); t[7] = (short)f2bf(x1.w);
      } else {
        t = *(const s16x8*)((const bfraw*)Xv + (size_t)arow * NF + kt * 32 + g * 8);
      }
    }
    afrag[kt] = t;
  }

  #pragma unroll
  for (int ct = 0; ct < 8; ++ct) {
    f32x4 acc = {0.f, 0.f, 0.f, 0.f};
    #pragma unroll
    for (int kt = 0; kt < 4; ++kt) {
      s16x8 b = *(const s16x8*)&Wb[(((ct * 4 + kt) * 64) + lane) * 8];
      acc = __builtin_amdgcn_mfma_f32_16x16x32_bf16(afrag[kt], b, acc, 0, 0, 0);
    }
    #pragma unroll
    for (int r = 0; r < 4; ++r) {
      stage[wv][g * 4 + r][ct * 16 + (lane & 15)] = f2bf(acc[r]);
    }
  }
  __syncthreads();
  int rr = lane >> 2;
  int cc = (lane & 3) * 32;
  int grow = rowBase + rr;
  if (grow < n) {
    #pragma unroll
    for (int q = 0; q < 4; ++q) {
      uint4 v = *(const uint4*)&stage[wv][rr][cc + q * 8];
      *(uint4*)&Tb[(size_t)grow * NF + cc + q * 8] = v;
    }
  }
}

// ---------------- MFMA GEMM: T40[n][64](bf16) = h2[n][128] @ W3pad[128][48] ----------------

__global__ __launch_bounds__(256) void gemm40_mfma_kernel(const bfraw* __restrict__ X,
                                                          const bfraw* __restrict__ Wb3,
                                                          bfraw* __restrict__ T40, int n) {
  __shared__ __align__(16) bfraw stage[4][16][72];
  int wv = threadIdx.x >> 6;
  int lane = threadIdx.x & 63;
  int rowBase = blockIdx.x * 64 + wv * 16;
  int arow = rowBase + (lane & 15);
  int g = lane >> 4;
  bool rv = arow < n;

  s16x8 afrag[4];
  #pragma unroll
  for (int kt = 0; kt < 4; ++kt) {
    s16x8 t = {0, 0, 0, 0, 0, 0, 0, 0};
    if (rv) t = *(const s16x8*)&X[(size_t)arow * NF + kt * 32 + g * 8];
    afrag[kt] = t;
  }

  #pragma unroll
  for (int ct = 0; ct < 3; ++ct) {
    f32x4 acc = {0.f, 0.f, 0.f, 0.f};
    #pragma unroll
    for (int kt = 0; kt < 4; ++kt) {
      s16x8 b = *(const s16x8*)&Wb3[(((ct * 4 + kt) * 64) + lane) * 8];
      acc = __builtin_amdgcn_mfma_f32_16x16x32_bf16(afrag[kt], b, acc, 0, 0, 0);
    }
    #pragma unroll
    for (int r = 0; r < 4; ++r) {
      stage[wv][g * 4 + r][ct * 16 + (lane & 15)] = f2bf(acc[r]);
    }
  }
  #pragma unroll
  for (int r = 0; r < 4; ++r) stage[wv][g * 4 + r][48 + (lane & 15)] = 0;
  __syncthreads();
  int rr = lane >> 2;
  int cc = (lane & 3) * 16;
  int grow = rowBase + rr;
  if (grow < n) {
    uint4 v0 = *(const uint4*)&stage[wv][rr][cc];
    uint4 v1 = *(const uint4*)&stage[wv][rr][cc + 8];
    *(uint4*)&T40[(size_t)grow * 64 + cc] = v0;
    *(uint4*)&T40[(size_t)grow * 64 + cc + 8] = v1;
  }
}

// ---------------- aggregation (pull), bf16 gather, node-major, 128 feats ----------------
// 4 edge streams x 16 lanes; 4-deep unrolled main loop: 16 row-gathers in flight
// per wave (matches mean degree 16 -> typically one main iteration per node).

#define ACC8(W_, Q_)                                                          \
  a[0] = fmaf(W_, bfLo(Q_.x), a[0]); a[1] = fmaf(W_, bfHi(Q_.x), a[1]);       \
  a[2] = fmaf(W_, bfLo(Q_.y), a[2]); a[3] = fmaf(W_, bfHi(Q_.y), a[3]);       \
  a[4] = fmaf(W_, bfLo(Q_.z), a[4]); a[5] = fmaf(W_, bfHi(Q_.z), a[5]);       \
  a[6] = fmaf(W_, bfLo(Q_.w), a[6]); a[7] = fmaf(W_, bfHi(Q_.w), a[7]);

template <bool RELU, bool RES, bool BIAS, bool OUTBF>
__global__ __launch_bounds__(256) void agg128_kernel(const bfraw* __restrict__ Tb,
                                                     const int* __restrict__ rp,
                                                     const unsigned* __restrict__ ecsr,
                                                     const float* __restrict__ bias,
                                                     const bfraw* __restrict__ Hres,
                                                     void* __restrict__ HoutV, int n) {
  int node = (blockIdx.x * 256 + threadIdx.x) >> 6;
  int lane = threadIdx.x & 63;
  if (node >= n) return;
  int st = lane >> 4;  // edge-stream 0..3
  int fl = lane & 15;  // features 8*fl .. 8*fl+7
  int beg = rp[node], end = rp[node + 1];
  float a[8];
  #pragma unroll
  for (int i = 0; i < 8; ++i) a[i] = 0.f;
  int eidx = beg + st;
  // main: 4 edges per stream per iteration (meta loads first, then gathers, then FMAs)
  for (; eidx + 12 < end; eidx += 16) {
    unsigned e0 = __builtin_nontemporal_load(&ecsr[eidx]);
    unsigned e1 = __builtin_nontemporal_load(&ecsr[eidx + 4]);
    unsigned e2 = __builtin_nontemporal_load(&ecsr[eidx + 8]);
    unsigned e3 = __builtin_nontemporal_load(&ecsr[eidx + 12]);
    uint4 q0 = *(const uint4*)&Tb[(size_t)(e0 >> 15) * NF + fl * 8];
    uint4 q1 = *(const uint4*)&Tb[(size_t)(e1 >> 15) * NF + fl * 8];
    uint4 q2 = *(const uint4*)&Tb[(size_t)(e2 >> 15) * NF + fl * 8];
    uint4 q3 = *(const uint4*)&Tb[(size_t)(e3 >> 15) * NF + fl * 8];
    float w0 = h15tof(e0), w1 = h15tof(e1), w2 = h15tof(e2), w3 = h15tof(e3);
    ACC8(w0, q0); ACC8(w1, q1); ACC8(w2, q2); ACC8(w3, q3);
  }
  for (; eidx + 4 < end; eidx += 8) {
    unsigned e0 = __builtin_nontemporal_load(&ecsr[eidx]);
    unsigned e1 = __builtin_nontemporal_load(&ecsr[eidx + 4]);
    uint4 q0 = *(const uint4*)&Tb[(size_t)(e0 >> 15) * NF + fl * 8];
    uint4 q1 = *(const uint4*)&Tb[(size_t)(e1 >> 15) * NF + fl * 8];
    float w0 = h15tof(e0), w1 = h15tof(e1);
    ACC8(w0, q0); ACC8(w1, q1);
  }
  if (eidx < end) {
    unsigned e0 = __builtin_nontemporal_load(&ecsr[eidx]);
    uint4 q0 = *(const uint4*)&Tb[(size_t)(e0 >> 15) * NF + fl * 8];
    float w0 = h15tof(e0);
    ACC8(w0, q0);
  }
  #pragma unroll
  for (int i = 0; i < 8; ++i) {
    a[i] += __shfl_xor(a[i], 16);
    a[i] += __shfl_xor(a[i], 32);
  }
  if (st == 0) {
    if (BIAS) {
      float4 b0 = *(const float4*)&bias[fl * 8];
      float4 b1 = *(const float4*)&bias[fl * 8 + 4];
      a[0] += b0.x; a[1] += b0.y; a[2] += b0.z; a[3] += b0.w;
      a[4] += b1.x; a[5] += b1.y; a[6] += b1.z; a[7] += b1.w;
    }
    if (RELU) {
      #pragma unroll
      for (int i = 0; i < 8; ++i) a[i] = fmaxf(a[i], 0.f);
    }
    if (RES) {
      uint4 r = *(const uint4*)&Hres[(size_t)node * NF + fl * 8];
      a[0] += bfLo(r.x); a[1] += bfHi(r.x);
      a[2] += bfLo(r.y); a[3] += bfHi(r.y);
      a[4] += bfLo(r.z); a[5] += bfHi(r.z);
      a[6] += bfLo(r.w); a[7] += bfHi(r.w);
    }
    if (OUTBF) {
      bfraw* Hout = (bfraw*)HoutV;
      uint4 o;
      o.x = ((unsigned)f2bf(a[1]) << 16) | f2bf(a[0]);
      o.y = ((unsigned)f2bf(a[3]) << 16) | f2bf(a[2]);
      o.z = ((unsigned)f2bf(a[5]) << 16) | f2bf(a[4]);
      o.w = ((unsigned)f2bf(a[7]) << 16) | f2bf(a[6]);
      *(uint4*)&Hout[(size_t)node * NF + fl * 8] = o;
    } else {
      float* Hout = (float*)HoutV;
      float4 o0, o1;
      o0.x = a[0]; o0.y = a[1]; o0.z = a[2]; o0.w = a[3];
      o1.x = a[4]; o1.y = a[5]; o1.z = a[6]; o1.w = a[7];
      *(float4*)&Hout[(size_t)node * NF + fl * 8] = o0;
      *(float4*)&Hout[(size_t)node * NF + fl * 8 + 4] = o1;
    }
  }
}

// ---------------- final: out = log_softmax(agg40(T40) + b3) ----------------

#define ACC4(W_, Q_)                                                      \
  a0 = fmaf(W_, bfLo(Q_.x), a0); a1 = fmaf(W_, bfHi(Q_.x), a1);           \
  a2 = fmaf(W_, bfLo(Q_.y), a2); a3 = fmaf(W_, bfHi(Q_.y), a3);

__global__ __launch_bounds__(256) void agg40_lsm_kernel(const bfraw* __restrict__ T40,
                                                        const int* __restrict__ rp,
                                                        const unsigned* __restrict__ ecsr,
                                                        const float* __restrict__ bias,
                                                        float* __restrict__ out, int n) {
  int node = (blockIdx.x * 256 + threadIdx.x) >> 6;
  int lane = threadIdx.x & 63;
  if (node >= n) return;
  int st = lane >> 4;  // edge-stream 0..3
  int fl = lane & 15;  // cols 4*fl .. 4*fl+3
  int beg = rp[node], end = rp[node + 1];
  float a0 = 0.f, a1 = 0.f, a2 = 0.f, a3 = 0.f;
  int eidx = beg + st;
  for (; eidx + 12 < end; eidx += 16) {
    unsigned e0 = __builtin_nontemporal_load(&ecsr[eidx]);
    unsigned e1 = __builtin_nontemporal_load(&ecsr[eidx + 4]);
    unsigned e2 = __builtin_nontemporal_load(&ecsr[eidx + 8]);
    unsigned e3 = __builtin_nontemporal_load(&ecsr[eidx + 12]);
    uint2 q0 = *(const uint2*)&T40[(size_t)(e0 >> 15) * 64 + fl * 4];
    uint2 q1 = *(const uint2*)&T40[(size_t)(e1 >> 15) * 64 + fl * 4];
    uint2 q2 = *(const uint2*)&T40[(size_t)(e2 >> 15) * 64 + fl * 4];
    uint2 q3 = *(const uint2*)&T40[(size_t)(e3 >> 15) * 64 + fl * 4];
    float w0 = h15tof(e0), w1 = h15tof(e1), w2 = h15tof(e2), w3 = h15tof(e3);
    ACC4(w0, q0); ACC4(w1, q1); ACC4(w2, q2); ACC4(w3, q3);
  }
  for (; eidx + 4 < end; eidx += 8) {
    unsigned e0 = __builtin_nontemporal_load(&ecsr[eidx]);
    unsigned e1 = __builtin_nontemporal_load(&ecsr[eidx + 4]);
    uint2 q0 = *(const uint2*)&T40[(size_t)(e0 >> 15) * 64 + fl * 4];
    uint2 q1 = *(const uint2*)&T40[(size_t)(e1 >> 15) * 64 + fl * 4];
    float w0 = h15tof(e0), w1 = h15tof(e1);
    ACC4(w0, q0); ACC4(w1, q1);
  }
  if (eidx < end) {
    unsigned e0 = __builtin_nontemporal_load(&ecsr[eidx]);
    uint2 q0 = *(const uint2*)&T40[(size_t)(e0 >> 15) * 64 + fl * 4];
    float w0 = h15tof(e0);
    ACC4(w0, q0);
  }
  a0 += __shfl_xor(a0, 16); a0 += __shfl_xor(a0, 32);
  a1 += __shfl_xor(a1, 16); a1 += __shfl_xor(a1, 32);
  a2 += __shfl_xor(a2, 16); a2 += __shfl_xor(a2, 32);
  a3 += __shfl_xor(a3, 16); a3 += __shfl_xor(a3, 32);
  if (st == 0) {
    bool v = fl < 10;
    if (v) {
      float4 b = *(const float4*)&bias[fl * 4];
      a0 += b.x; a1 += b.y; a2 += b.z; a3 += b.w;
    }
    float lm = v ? fmaxf(fmaxf(a0, a1), fmaxf(a2, a3)) : -INFINITY;
    #pragma unroll
    for (int off = 1; off < 16; off <<= 1) lm = fmaxf(lm, __shfl_xor(lm, off));
    float ls = v ? (expf(a0 - lm) + expf(a1 - lm) + expf(a2 - lm) + expf(a3 - lm)) : 0.f;
    #pragma unroll
    for (int off = 1; off < 16; off <<= 1) ls += __shfl_xor(ls, off);
    float lse = lm + logf(ls);
    if (v) {
      float4 o;
      o.x = a0 - lse; o.y = a1 - lse; o.z = a2 - lse; o.w = a3 - lse;
      *(float4*)&out[(size_t)node * NC + fl * 4] = o;
    }
  }
}

// ---------------- launch ----------------

extern "C" void kernel_launch(void* const* d_in, const int* in_sizes, int n_in,
                              void* d_out, int out_size, void* d_ws, size_t ws_size,
                              hipStream_t stream) {
  const float* x   = (const float*)d_in[0];
  const int*   src = (const int*)d_in[1];
  const int*   tgt = (const int*)d_in[2];
  const float* mw  = (const float*)d_in[3];
  const float* W0  = (const float*)d_in[4];
  const float* b0  = (const float*)d_in[5];
  const float* W1  = (const float*)d_in[6];
  const float* b1  = (const float*)d_in[7];
  const float* W2  = (const float*)d_in[8];
  const float* b2  = (const float*)d_in[9];
  const float* W3  = (const float*)d_in[10];
  const float* b3  = (const float*)d_in[11];
  int n = in_sizes[0] / NF;
  int e = in_sizes[1];
  float* out = (float*)d_out;

  char* ws = (char*)d_ws;
  size_t nbB = (((size_t)n * NF * sizeof(bfraw)) + 255) / 256 * 256; // bf16 [N,128]
  bfraw* bufT  = (bfraw*)(ws);                   // transform out (bf16), also T40 (stride 64)
  bfraw* bufH0 = (bfraw*)(ws + nbB);             // h0 / h2
  bfraw* bufH1 = (bfraw*)(ws + 2 * nbB);         // h1
  // slab staging aliases bufH0+bufH1 (dead until after P2): 512*8*1024*8 = 33.5 MB
  long long* slab = (long long*)(ws + nbB);
  char* p = ws + 3 * nbB;
  bfraw* Wb = (bfraw*)p;   // 3 gemm128 packs + 1 gemm40 pack
  p += (((3 * 8 + 3) * 4 * 64 * 8 * sizeof(bfraw)) + 255) / 256 * 256;
  int* rp = (int*)p;      p += (((size_t)(n + 1) * 4) + 255) / 256 * 256;
  int* fill = (int*)p;    p += (((size_t)n * 4) + 255) / 256 * 256;
  int* bsum = (int*)p;    p += 4096;
  int* slabcnt = (int*)p; p += ((NBLK * 8 * 4) + 255) / 256 * 256;
  unsigned* ecsr = (unsigned*)p;

  bfraw* Wb3 = Wb + 3 * 8 * 4 * 64 * 8;

  hipMemsetAsync(fill, 0, (size_t)n * 4, stream);
  int nb1 = (n + 1023) / 1024;
  wpack_kernel<<<(3 * NF * NF + 255) / 256, 256, 0, stream>>>(W0, W1, W2, Wb);
  wpack40_kernel<<<(NF * 48 + 255) / 256, 256, 0, stream>>>(W3, Wb3);
  p1_kernel<<<NBLK, 256, 0, stream>>>(src, tgt, mw, slabcnt, slab, e, n);
  count2_kernel<<<128, 256, 0, stream>>>(slab, slabcnt, fill, n);
  scan1_kernel<<<nb1, 1024, 0, stream>>>(fill, rp, bsum, n);
  scan2_kernel<<<1, 1024, 0, stream>>>(bsum, nb1, &rp[n]);
  scan3_kernel<<<(n + 255) / 256, 256, 0, stream>>>(rp, fill, bsum, n);
  p2_kernel<<<NBLK, 256, 0, stream>>>(slab, slabcnt, fill, ecsr);

  int gb = (n + 63) / 64;
  int ab = (n + 3) / 4;
  // L0: h0 = relu(agg(x@W0) + b0)                       (h0 bf16)
  gemm128_mfma_kernel<true><<<gb, 256, 0, stream>>>(x, Wb, bufT, n);
  agg128_kernel<true, false, true, true><<<ab, 256, 0, stream>>>(
      bufT, rp, ecsr, b0, nullptr, bufH0, n);
  // L1: h1 = relu(agg(h0@W1) + b1) + h0                 (h1 bf16)
  gemm128_mfma_kernel<false><<<gb, 256, 0, stream>>>(bufH0, Wb + 8 * 4 * 64 * 8, bufT, n);
  agg128_kernel<true, true, true, true><<<ab, 256, 0, stream>>>(
      bufT, rp, ecsr, b1, bufH0, bufH1, n);
  // L2: h2 = relu(agg(h1@W2) + b2) + h1                 (h2 bf16, reuses h0 buf)
  gemm128_mfma_kernel<false><<<gb, 256, 0, stream>>>(bufH1, Wb + 2 * 8 * 4 * 64 * 8, bufT, n);
  agg128_kernel<true, true, true, true><<<ab, 256, 0, stream>>>(
      bufT, rp, ecsr, b2, bufH1, bufH0, n);
  // Final: T40 = h2 @ W3pad (bf16, stride 64) ; out = log_softmax(agg40(T40) + b3)
  gemm40_mfma_kernel<<<gb, 256, 0, stream>>>(bufH0, Wb3, bufT, n);
  agg40_lsm_kernel<<<ab, 256, 0, stream>>>(bufT, rp, ecsr, b3, out, n);
}

// Round 18
// 432.803 us; speedup vs baseline: 1.1379x; 1.0687x over previous
//
#include <hip/hip_runtime.h>
#include <hip/hip_fp16.h>
#include <math.h>

#define NF 128
#define NC 40
#define NBLK 512    // p1 blocks, each owns a private slab
#define NPART 64    // node-range buckets: bk = t >> PSHIFT (single-writer scatter)
#define PSHIFT 11   // 64 buckets x 2048 nodes covers n < 131072
#define SCAP 128    // per-(block,bucket) capacity (mean 64, +8 sigma, guarded)
#define HSZ 2048    // bucket width

typedef unsigned short bfraw;
typedef float f32x4 __attribute__((ext_vector_type(4)));
typedef short s16x8 __attribute__((ext_vector_type(8)));

__device__ __forceinline__ float bfLo(unsigned u) {
  return __uint_as_float(u << 16);
}
__device__ __forceinline__ float bfHi(unsigned u) {
  return __uint_as_float(u & 0xffff0000u);
}
__device__ __forceinline__ unsigned short f2bf(float f) {
  unsigned u = __float_as_uint(f);
  u += 0x7fff + ((u >> 16) & 1);  // RNE
  return (unsigned short)(u >> 16);
}
// weight in [0,1): positive fp16, 15 bits (no sign)
__device__ __forceinline__ unsigned short f2h15(float f) {
  __half h = __float2half(f);
  __half_raw hr = static_cast<__half_raw>(h);
  return (unsigned short)(hr.x & 0x7FFF);
}
__device__ __forceinline__ float h15tof(unsigned rec) {
  __half_raw hr;
  hr.x = (unsigned short)(rec & 0x7FFF);
  __half h = static_cast<__half>(hr);
  return __half2float(h);
}

// ---------------- CSR build: P1 — stream + 64-bucket slab append (LDS cursors) ----------------

__global__ __launch_bounds__(256) void p1_kernel(const int* __restrict__ src,
                                                 const int* __restrict__ tgt,
                                                 const float* __restrict__ mw,
                                                 int* __restrict__ slabcnt,
                                                 long long* __restrict__ slab,
                                                 int e, int n) {
  __shared__ int lcnt[NPART];
  int B = blockIdx.x;
  int tid = threadIdx.x;
  if (tid < NPART) lcnt[tid] = 0;
  __syncthreads();
  int lo = (int)(((long long)e * B) / NBLK);
  int hi = (int)(((long long)e * (B + 1)) / NBLK);
  long long* myslab = slab + (size_t)B * NPART * SCAP;
  for (int i = lo + tid; i < hi; i += 256) {
    int t = __builtin_nontemporal_load(&tgt[i]);
    int sr = __builtin_nontemporal_load(&src[i]);
    float w = __builtin_nontemporal_load(&mw[i]);
    int bk = t >> PSHIFT;  // same partition fn as count2/p2 ranges
    long long v = ((long long)t << 32) |
                  (long long)(((unsigned)sr << 15) | f2h15(w));
    int pos = atomicAdd(&lcnt[bk], 1);  // LDS atomic
    if (pos < SCAP) myslab[(size_t)bk * SCAP + pos] = v;
  }
  __syncthreads();
  if (tid < NPART) {
    int c = lcnt[tid];
    slabcnt[B * NPART + tid] = (c < SCAP) ? c : SCAP;
  }
}

// ---------------- CSR build: count2 — one block per range, LDS histogram, plain stores ----------------

__global__ __launch_bounds__(1024) void count2_kernel(const long long* __restrict__ slab,
                                                      const int* __restrict__ slabcnt,
                                                      int* __restrict__ cnt, int n) {
  __shared__ int hist[HSZ];
  __shared__ int scnt[NBLK];
  int b = blockIdx.x;
  int tid = threadIdx.x;
  int lo = b << PSHIFT;
  int hi = (b + 1) << PSHIFT;
  if (hi > n) hi = n;
  int sz = hi - lo;
  if (sz <= 0) return;
  for (int j = tid; j < sz; j += 1024) hist[j] = 0;
  for (int j = tid; j < NBLK; j += 1024) scnt[j] = slabcnt[j * NPART + b];
  __syncthreads();
  for (int idx = tid; idx < NBLK * SCAP; idx += 1024) {
    int B = idx >> 7;   // / SCAP
    int i = idx & (SCAP - 1);
    if (i < scnt[B]) {
      long long v = __builtin_nontemporal_load(&slab[((size_t)B * NPART + b) * SCAP + i]);
      atomicAdd(&hist[(int)(v >> 32) - lo], 1);  // LDS atomic
    }
  }
  __syncthreads();
  for (int j = tid; j < sz; j += 1024) cnt[lo + j] = hist[j];  // single writer
}

// ---------------- CSR build: P2 — one block per range, LDS cursors, private ecsr slice ----------------

__global__ __launch_bounds__(1024) void p2_kernel(const long long* __restrict__ slab,
                                                  const int* __restrict__ slabcnt,
                                                  const int* __restrict__ rp,
                                                  unsigned* __restrict__ ecsr, int n) {
  __shared__ int cur[HSZ];
  __shared__ int scnt[NBLK];
  int b = blockIdx.x;
  int tid = threadIdx.x;
  int lo = b << PSHIFT;
  int hi = (b + 1) << PSHIFT;
  if (hi > n) hi = n;
  int sz = hi - lo;
  if (sz <= 0) return;
  for (int j = tid; j < sz; j += 1024) cur[j] = rp[lo + j];
  for (int j = tid; j < NBLK; j += 1024) scnt[j] = slabcnt[j * NPART + b];
  __syncthreads();
  for (int idx = tid; idx < NBLK * SCAP; idx += 1024) {
    int B = idx >> 7;
    int i = idx & (SCAP - 1);
    if (i < scnt[B]) {
      long long v = __builtin_nontemporal_load(&slab[((size_t)B * NPART + b) * SCAP + i]);
      int t = (int)(v >> 32);
      int pos = atomicAdd(&cur[t - lo], 1);  // LDS atomic
      ecsr[pos] = (unsigned)(v & 0xffffffffLL);
    }
  }
}

// ---------------- scans ----------------

__global__ __launch_bounds__(1024) void scan1_kernel(const int* __restrict__ cnt,
                                                     int* __restrict__ rp,
                                                     int* __restrict__ bsum, int n) {
  __shared__ int wsum[16];
  int tid = threadIdx.x, lane = tid & 63, wid = tid >> 6;
  int i = blockIdx.x * 1024 + tid;
  int v = (i < n) ? cnt[i] : 0;
  int x = v;
  #pragma unroll
  for (int off = 1; off < 64; off <<= 1) {
    int t = __shfl_up(x, off);
    if (lane >= off) x += t;
  }
  if (lane == 63) wsum[wid] = x;
  __syncthreads();
  if (wid == 0) {
    int ws = (lane < 16) ? wsum[lane] : 0;
    int y = ws;
    #pragma unroll
    for (int off = 1; off < 16; off <<= 1) {
      int t = __shfl_up(y, off);
      if (lane >= off) y += t;
    }
    if (lane < 16) wsum[lane] = y - ws;
  }
  __syncthreads();
  int incl = x + wsum[wid];
  if (i < n) rp[i] = incl - v;
  if (tid == 1023) bsum[blockIdx.x] = incl;
}

__global__ __launch_bounds__(1024) void scan2_kernel(int* __restrict__ bsum, int nb,
                                                     int* __restrict__ rp_n) {
  __shared__ int wsum[16];
  int tid = threadIdx.x, lane = tid & 63, wid = tid >> 6;
  int v = (tid < nb) ? bsum[tid] : 0;
  int x = v;
  #pragma unroll
  for (int off = 1; off < 64; off <<= 1) {
    int t = __shfl_up(x, off);
    if (lane >= off) x += t;
  }
  if (lane == 63) wsum[wid] = x;
  __syncthreads();
  if (wid == 0) {
    int ws = (lane < 16) ? wsum[lane] : 0;
    int y = ws;
    #pragma unroll
    for (int off = 1; off < 16; off <<= 1) {
      int t = __shfl_up(y, off);
      if (lane >= off) y += t;
    }
    if (lane < 16) wsum[lane] = y - ws;
  }
  __syncthreads();
  int incl = x + wsum[wid];
  if (tid < nb) bsum[tid] = incl - v;
  if (tid == 1023) *rp_n = incl;
}

__global__ __launch_bounds__(256) void scan3_kernel(int* __restrict__ rp,
                                                    const int* __restrict__ bsum, int n) {
  int i = blockIdx.x * 256 + threadIdx.x;
  if (i < n) rp[i] += bsum[i >> 10];
}

// ---------------- weight pack: W[128][128] fp32 -> B-fragment bf16 layout ----------------

__global__ __launch_bounds__(256) void wpack_kernel(const float* __restrict__ W0,
                                                    const float* __restrict__ W1,
                                                    const float* __restrict__ W2,
                                                    bfraw* __restrict__ Wb) {
  int id = blockIdx.x * 256 + threadIdx.x;
  if (id >= 3 * NF * NF) return;
  int w = id >> 14;
  int el = id & 16383;
  int k = el >> 7;
  int col = el & 127;
  const float* W = (w == 0) ? W0 : ((w == 1) ? W1 : W2);
  float v = W[k * NF + col];
  int ct = col >> 4;
  int kt = k >> 5;
  int g = (k & 31) >> 3;
  int j = k & 7;
  int ln = g * 16 + (col & 15);
  Wb[((((w * 8 + ct) * 4 + kt) * 64) + ln) * 8 + j] = f2bf(v);
}

// W3[128][40] fp32 -> B-frag layout over 48 cols (cols 40..47 zero)
__global__ __launch_bounds__(256) void wpack40_kernel(const float* __restrict__ W3,
                                                      bfraw* __restrict__ Wb3) {
  int id = blockIdx.x * 256 + threadIdx.x;
  if (id >= NF * 48) return;
  int k = id / 48;
  int col = id % 48;
  float v = (col < NC) ? W3[k * NC + col] : 0.f;
  int ct = col >> 4;
  int kt = k >> 5;
  int g = (k & 31) >> 3;
  int j = k & 7;
  int ln = g * 16 + (col & 15);
  Wb3[(((ct * 4 + kt) * 64) + ln) * 8 + j] = f2bf(v);
}

// ---------------- MFMA GEMM: Tb[n][128](bf16) = X[n][128] @ W[128][128] ----------------

template <bool INF32>
__global__ __launch_bounds__(256) void gemm128_mfma_kernel(const void* __restrict__ Xv,
                                                           const bfraw* __restrict__ Wb,
                                                           bfraw* __restrict__ Tb, int n) {
  __shared__ __align__(16) bfraw stage[4][16][NF + 8];
  int wv = threadIdx.x >> 6;
  int lane = threadIdx.x & 63;
  int rowBase = blockIdx.x * 64 + wv * 16;
  int arow = rowBase + (lane & 15);
  int g = lane >> 4;
  bool rv = arow < n;

  s16x8 afrag[4];
  #pragma unroll
  for (int kt = 0; kt < 4; ++kt) {
    s16x8 t = {0, 0, 0, 0, 0, 0, 0, 0};
    if (rv) {
      if (INF32) {
        const float* xr = (const float*)Xv + (size_t)arow * NF + kt * 32 + g * 8;
        float4 x0 = *(const float4*)xr;
        float4 x1 = *(const float4*)(xr + 4);
        t[0] = (short)f2bf(x0.x); t[1] = (short)f2bf(x0.y);
        t[2] = (short)f2bf(x0.z); t[3] = (short)f2bf(x0.w);
        t[4] = (short)f2bf(x1.x); t[5] = (short)f2bf(x1.y);
        t[6] = (short)f2bf(x1.z); t[7] = (short)f2bf(x1.w);
      } else {
        t = *(const s16x8*)((const bfraw*)Xv + (size_t)arow * NF + kt * 32 + g * 8);
      }
    }
    afrag[kt] = t;
  }

  #pragma unroll
  for (int ct = 0; ct < 8; ++ct) {
    f32x4 acc = {0.f, 0.f, 0.f, 0.f};
    #pragma unroll
    for (int kt = 0; kt < 4; ++kt) {
      s16x8 b = *(const s16x8*)&Wb[(((ct * 4 + kt) * 64) + lane) * 8];
      acc = __builtin_amdgcn_mfma_f32_16x16x32_bf16(afrag[kt], b, acc, 0, 0, 0);
    }
    #pragma unroll
    for (int r = 0; r < 4; ++r) {
      stage[wv][g * 4 + r][ct * 16 + (lane & 15)] = f2bf(acc[r]);
    }
  }
  __syncthreads();
  int rr = lane >> 2;
  int cc = (lane & 3) * 32;
  int grow = rowBase + rr;
  if (grow < n) {
    #pragma unroll
    for (int q = 0; q < 4; ++q) {
      uint4 v = *(const uint4*)&stage[wv][rr][cc + q * 8];
      *(uint4*)&Tb[(size_t)grow * NF + cc + q * 8] = v;
    }
  }
}

// ---------------- MFMA GEMM: T40[n][64](bf16) = h2[n][128] @ W3pad[128][48] ----------------

__global__ __launch_bounds__(256) void gemm40_mfma_kernel(const bfraw* __restrict__ X,
                                                          const bfraw* __restrict__ Wb3,
                                                          bfraw* __restrict__ T40, int n) {
  __shared__ __align__(16) bfraw stage[4][16][72];
  int wv = threadIdx.x >> 6;
  int lane = threadIdx.x & 63;
  int rowBase = blockIdx.x * 64 + wv * 16;
  int arow = rowBase + (lane & 15);
  int g = lane >> 4;
  bool rv = arow < n;

  s16x8 afrag[4];
  #pragma unroll
  for (int kt = 0; kt < 4; ++kt) {
    s16x8 t = {0, 0, 0, 0, 0, 0, 0, 0};
    if (rv) t = *(const s16x8*)&X[(size_t)arow * NF + kt * 32 + g * 8];
    afrag[kt] = t;
  }

  #pragma unroll
  for (int ct = 0; ct < 3; ++ct) {
    f32x4 acc = {0.f, 0.f, 0.f, 0.f};
    #pragma unroll
    for (int kt = 0; kt < 4; ++kt) {
      s16x8 b = *(const s16x8*)&Wb3[(((ct * 4 + kt) * 64) + lane) * 8];
      acc = __builtin_amdgcn_mfma_f32_16x16x32_bf16(afrag[kt], b, acc, 0, 0, 0);
    }
    #pragma unroll
    for (int r = 0; r < 4; ++r) {
      stage[wv][g * 4 + r][ct * 16 + (lane & 15)] = f2bf(acc[r]);
    }
  }
  #pragma unroll
  for (int r = 0; r < 4; ++r) stage[wv][g * 4 + r][48 + (lane & 15)] = 0;
  __syncthreads();
  int rr = lane >> 2;
  int cc = (lane & 3) * 16;
  int grow = rowBase + rr;
  if (grow < n) {
    uint4 v0 = *(const uint4*)&stage[wv][rr][cc];
    uint4 v1 = *(const uint4*)&stage[wv][rr][cc + 8];
    *(uint4*)&T40[(size_t)grow * 64 + cc] = v0;
    *(uint4*)&T40[(size_t)grow * 64 + cc + 8] = v1;
  }
}

// ---------------- aggregation (pull), bf16 gather, node-major, 128 feats ----------------
// 4 edge streams x 16 lanes; 4-deep unrolled main loop: 16 row-gathers in flight.

#define ACC8(W_, Q_)                                                          \
  a[0] = fmaf(W_, bfLo(Q_.x), a[0]); a[1] = fmaf(W_, bfHi(Q_.x), a[1]);       \
  a[2] = fmaf(W_, bfLo(Q_.y), a[2]); a[3] = fmaf(W_, bfHi(Q_.y), a[3]);       \
  a[4] = fmaf(W_, bfLo(Q_.z), a[4]); a[5] = fmaf(W_, bfHi(Q_.z), a[5]);       \
  a[6] = fmaf(W_, bfLo(Q_.w), a[6]); a[7] = fmaf(W_, bfHi(Q_.w), a[7]);

template <bool RELU, bool RES, bool BIAS, bool OUTBF>
__global__ __launch_bounds__(256) void agg128_kernel(const bfraw* __restrict__ Tb,
                                                     const int* __restrict__ rp,
                                                     const unsigned* __restrict__ ecsr,
                                                     const float* __restrict__ bias,
                                                     const bfraw* __restrict__ Hres,
                                                     void* __restrict__ HoutV, int n) {
  int node = (blockIdx.x * 256 + threadIdx.x) >> 6;
  int lane = threadIdx.x & 63;
  if (node >= n) return;
  int st = lane >> 4;  // edge-stream 0..3
  int fl = lane & 15;  // features 8*fl .. 8*fl+7
  int beg = rp[node], end = rp[node + 1];
  float a[8];
  #pragma unroll
  for (int i = 0; i < 8; ++i) a[i] = 0.f;
  int eidx = beg + st;
  for (; eidx + 12 < end; eidx += 16) {
    unsigned e0 = __builtin_nontemporal_load(&ecsr[eidx]);
    unsigned e1 = __builtin_nontemporal_load(&ecsr[eidx + 4]);
    unsigned e2 = __builtin_nontemporal_load(&ecsr[eidx + 8]);
    unsigned e3 = __builtin_nontemporal_load(&ecsr[eidx + 12]);
    uint4 q0 = *(const uint4*)&Tb[(size_t)(e0 >> 15) * NF + fl * 8];
    uint4 q1 = *(const uint4*)&Tb[(size_t)(e1 >> 15) * NF + fl * 8];
    uint4 q2 = *(const uint4*)&Tb[(size_t)(e2 >> 15) * NF + fl * 8];
    uint4 q3 = *(const uint4*)&Tb[(size_t)(e3 >> 15) * NF + fl * 8];
    float w0 = h15tof(e0), w1 = h15tof(e1), w2 = h15tof(e2), w3 = h15tof(e3);
    ACC8(w0, q0); ACC8(w1, q1); ACC8(w2, q2); ACC8(w3, q3);
  }
  for (; eidx + 4 < end; eidx += 8) {
    unsigned e0 = __builtin_nontemporal_load(&ecsr[eidx]);
    unsigned e1 = __builtin_nontemporal_load(&ecsr[eidx + 4]);
    uint4 q0 = *(const uint4*)&Tb[(size_t)(e0 >> 15) * NF + fl * 8];
    uint4 q1 = *(const uint4*)&Tb[(size_t)(e1 >> 15) * NF + fl * 8];
    float w0 = h15tof(e0), w1 = h15tof(e1);
    ACC8(w0, q0); ACC8(w1, q1);
  }
  if (eidx < end) {
    unsigned e0 = __builtin_nontemporal_load(&ecsr[eidx]);
    uint4 q0 = *(const uint4*)&Tb[(size_t)(e0 >> 15) * NF + fl * 8];
    float w0 = h15tof(e0);
    ACC8(w0, q0);
  }
  #pragma unroll
  for (int i = 0; i < 8; ++i) {
    a[i] += __shfl_xor(a[i], 16);
    a[i] += __shfl_xor(a[i], 32);
  }
  if (st == 0) {
    if (BIAS) {
      float4 b0 = *(const float4*)&bias[fl * 8];
      float4 b1 = *(const float4*)&bias[fl * 8 + 4];
      a[0] += b0.x; a[1] += b0.y; a[2] += b0.z; a[3] += b0.w;
      a[4] += b1.x; a[5] += b1.y; a[6] += b1.z; a[7] += b1.w;
    }
    if (RELU) {
      #pragma unroll
      for (int i = 0; i < 8; ++i) a[i] = fmaxf(a[i], 0.f);
    }
    if (RES) {
      uint4 r = *(const uint4*)&Hres[(size_t)node * NF + fl * 8];
      a[0] += bfLo(r.x); a[1] += bfHi(r.x);
      a[2] += bfLo(r.y); a[3] += bfHi(r.y);
      a[4] += bfLo(r.z); a[5] += bfHi(r.z);
      a[6] += bfLo(r.w); a[7] += bfHi(r.w);
    }
    if (OUTBF) {
      bfraw* Hout = (bfraw*)HoutV;
      uint4 o;
      o.x = ((unsigned)f2bf(a[1]) << 16) | f2bf(a[0]);
      o.y = ((unsigned)f2bf(a[3]) << 16) | f2bf(a[2]);
      o.z = ((unsigned)f2bf(a[5]) << 16) | f2bf(a[4]);
      o.w = ((unsigned)f2bf(a[7]) << 16) | f2bf(a[6]);
      *(uint4*)&Hout[(size_t)node * NF + fl * 8] = o;
    } else {
      float* Hout = (float*)HoutV;
      float4 o0, o1;
      o0.x = a[0]; o0.y = a[1]; o0.z = a[2]; o0.w = a[3];
      o1.x = a[4]; o1.y = a[5]; o1.z = a[6]; o1.w = a[7];
      *(float4*)&Hout[(size_t)node * NF + fl * 8] = o0;
      *(float4*)&Hout[(size_t)node * NF + fl * 8 + 4] = o1;
    }
  }
}

// ---------------- final: out = log_softmax(agg40(T40) + b3) ----------------

#define ACC4(W_, Q_)                                                      \
  a0 = fmaf(W_, bfLo(Q_.x), a0); a1 = fmaf(W_, bfHi(Q_.x), a1);           \
  a2 = fmaf(W_, bfLo(Q_.y), a2); a3 = fmaf(W_, bfHi(Q_.y), a3);

__global__ __launch_bounds__(256) void agg40_lsm_kernel(const bfraw* __restrict__ T40,
                                                        const int* __restrict__ rp,
                                                        const unsigned* __restrict__ ecsr,
                                                        const float* __restrict__ bias,
                                                        float* __restrict__ out, int n) {
  int node = (blockIdx.x * 256 + threadIdx.x) >> 6;
  int lane = threadIdx.x & 63;
  if (node >= n) return;
  int st = lane >> 4;  // edge-stream 0..3
  int fl = lane & 15;  // cols 4*fl .. 4*fl+3
  int beg = rp[node], end = rp[node + 1];
  float a0 = 0.f, a1 = 0.f, a2 = 0.f, a3 = 0.f;
  int eidx = beg + st;
  for (; eidx + 12 < end; eidx += 16) {
    unsigned e0 = __builtin_nontemporal_load(&ecsr[eidx]);
    unsigned e1 = __builtin_nontemporal_load(&ecsr[eidx + 4]);
    unsigned e2 = __builtin_nontemporal_load(&ecsr[eidx + 8]);
    unsigned e3 = __builtin_nontemporal_load(&ecsr[eidx + 12]);
    uint2 q0 = *(const uint2*)&T40[(size_t)(e0 >> 15) * 64 + fl * 4];
    uint2 q1 = *(const uint2*)&T40[(size_t)(e1 >> 15) * 64 + fl * 4];
    uint2 q2 = *(const uint2*)&T40[(size_t)(e2 >> 15) * 64 + fl * 4];
    uint2 q3 = *(const uint2*)&T40[(size_t)(e3 >> 15) * 64 + fl * 4];
    float w0 = h15tof(e0), w1 = h15tof(e1), w2 = h15tof(e2), w3 = h15tof(e3);
    ACC4(w0, q0); ACC4(w1, q1); ACC4(w2, q2); ACC4(w3, q3);
  }
  for (; eidx + 4 < end; eidx += 8) {
    unsigned e0 = __builtin_nontemporal_load(&ecsr[eidx]);
    unsigned e1 = __builtin_nontemporal_load(&ecsr[eidx + 4]);
    uint2 q0 = *(const uint2*)&T40[(size_t)(e0 >> 15) * 64 + fl * 4];
    uint2 q1 = *(const uint2*)&T40[(size_t)(e1 >> 15) * 64 + fl * 4];
    float w0 = h15tof(e0), w1 = h15tof(e1);
    ACC4(w0, q0); ACC4(w1, q1);
  }
  if (eidx < end) {
    unsigned e0 = __builtin_nontemporal_load(&ecsr[eidx]);
    uint2 q0 = *(const uint2*)&T40[(size_t)(e0 >> 15) * 64 + fl * 4];
    float w0 = h15tof(e0);
    ACC4(w0, q0);
  }
  a0 += __shfl_xor(a0, 16); a0 += __shfl_xor(a0, 32);
  a1 += __shfl_xor(a1, 16); a1 += __shfl_xor(a1, 32);
  a2 += __shfl_xor(a2, 16); a2 += __shfl_xor(a2, 32);
  a3 += __shfl_xor(a3, 16); a3 += __shfl_xor(a3, 32);
  if (st == 0) {
    bool v = fl < 10;
    if (v) {
      float4 b = *(const float4*)&bias[fl * 4];
      a0 += b.x; a1 += b.y; a2 += b.z; a3 += b.w;
    }
    float lm = v ? fmaxf(fmaxf(a0, a1), fmaxf(a2, a3)) : -INFINITY;
    #pragma unroll
    for (int off = 1; off < 16; off <<= 1) lm = fmaxf(lm, __shfl_xor(lm, off));
    float ls = v ? (expf(a0 - lm) + expf(a1 - lm) + expf(a2 - lm) + expf(a3 - lm)) : 0.f;
    #pragma unroll
    for (int off = 1; off < 16; off <<= 1) ls += __shfl_xor(ls, off);
    float lse = lm + logf(ls);
    if (v) {
      float4 o;
      o.x = a0 - lse; o.y = a1 - lse; o.z = a2 - lse; o.w = a3 - lse;
      *(float4*)&out[(size_t)node * NC + fl * 4] = o;
    }
  }
}

// ---------------- launch ----------------

extern "C" void kernel_launch(void* const* d_in, const int* in_sizes, int n_in,
                              void* d_out, int out_size, void* d_ws, size_t ws_size,
                              hipStream_t stream) {
  const float* x   = (const float*)d_in[0];
  const int*   src = (const int*)d_in[1];
  const int*   tgt = (const int*)d_in[2];
  const float* mw  = (const float*)d_in[3];
  const float* W0  = (const float*)d_in[4];
  const float* b0  = (const float*)d_in[5];
  const float* W1  = (const float*)d_in[6];
  const float* b1  = (const float*)d_in[7];
  const float* W2  = (const float*)d_in[8];
  const float* b2  = (const float*)d_in[9];
  const float* W3  = (const float*)d_in[10];
  const float* b3  = (const float*)d_in[11];
  int n = in_sizes[0] / NF;
  int e = in_sizes[1];
  float* out = (float*)d_out;

  char* ws = (char*)d_ws;
  size_t nbB = (((size_t)n * NF * sizeof(bfraw)) + 255) / 256 * 256; // bf16 [N,128]
  bfraw* bufT  = (bfraw*)(ws);                   // transform out (bf16), also T40 (stride 64)
  bfraw* bufH0 = (bfraw*)(ws + nbB);             // h0 / h2
  bfraw* bufH1 = (bfraw*)(ws + 2 * nbB);         // h1
  // slab staging aliases bufH0+bufH1 (dead until after P2): 512*64*128*8 = 33.5 MB
  long long* slab = (long long*)(ws + nbB);
  char* p = ws + 3 * nbB;
  bfraw* Wb = (bfraw*)p;   // 3 gemm128 packs + 1 gemm40 pack
  p += (((3 * 8 + 3) * 4 * 64 * 8 * sizeof(bfraw)) + 255) / 256 * 256;
  int* rp = (int*)p;      p += (((size_t)(n + 1) * 4) + 255) / 256 * 256;
  int* fill = (int*)p;    p += (((size_t)n * 4) + 255) / 256 * 256;
  int* bsum = (int*)p;    p += 4096;
  int* slabcnt = (int*)p; p += ((NBLK * NPART * 4) + 255) / 256 * 256;
  unsigned* ecsr = (unsigned*)p;

  bfraw* Wb3 = Wb + 3 * 8 * 4 * 64 * 8;

  int nb1 = (n + 1023) / 1024;
  wpack_kernel<<<(3 * NF * NF + 255) / 256, 256, 0, stream>>>(W0, W1, W2, Wb);
  wpack40_kernel<<<(NF * 48 + 255) / 256, 256, 0, stream>>>(W3, Wb3);
  p1_kernel<<<NBLK, 256, 0, stream>>>(src, tgt, mw, slabcnt, slab, e, n);
  count2_kernel<<<NPART, 1024, 0, stream>>>(slab, slabcnt, fill, n);
  scan1_kernel<<<nb1, 1024, 0, stream>>>(fill, rp, bsum, n);
  scan2_kernel<<<1, 1024, 0, stream>>>(bsum, nb1, &rp[n]);
  scan3_kernel<<<(n + 255) / 256, 256, 0, stream>>>(rp, bsum, n);
  p2_kernel<<<NPART, 1024, 0, stream>>>(slab, slabcnt, rp, ecsr, n);

  int gb = (n + 63) / 64;
  int ab = (n + 3) / 4;
  // L0: h0 = relu(agg(x@W0) + b0)                       (h0 bf16)
  gemm128_mfma_kernel<true><<<gb, 256, 0, stream>>>(x, Wb, bufT, n);
  agg128_kernel<true, false, true, true><<<ab, 256, 0, stream>>>(
      bufT, rp, ecsr, b0, nullptr, bufH0, n);
  // L1: h1 = relu(agg(h0@W1) + b1) + h0                 (h1 bf16)
  gemm128_mfma_kernel<false><<<gb, 256, 0, stream>>>(bufH0, Wb + 8 * 4 * 64 * 8, bufT, n);
  agg128_kernel<true, true, true, true><<<ab, 256, 0, stream>>>(
      bufT, rp, ecsr, b1, bufH0, bufH1, n);
  // L2: h2 = relu(agg(h1@W2) + b2) + h1                 (h2 bf16, reuses h0 buf)
  gemm128_mfma_kernel<false><<<gb, 256, 0, stream>>>(bufH1, Wb + 2 * 8 * 4 * 64 * 8, bufT, n);
  agg128_kernel<true, true, true, true><<<ab, 256, 0, stream>>>(
      bufT, rp, ecsr, b2, bufH1, bufH0, n);
  // Final: T40 = h2 @ W3pad (bf16, stride 64) ; out = log_softmax(agg40(T40) + b3)
  gemm40_mfma_kernel<<<gb, 256, 0, stream>>>(bufH0, Wb3, bufT, n);
  agg40_lsm_kernel<<<ab, 256, 0, stream>>>(bufT, rp, ecsr, b3, out, n);
}